// Round 2
// baseline (283.435 us; speedup 1.0000x reference)
//
#include <hip/hip_runtime.h>
#include <math.h>

// Problem constants
#define B_  4
#define C_  16
#define T_  32
#define H_  128
#define W_  128
#define KF  4
#define TAU 0.1
#define EPS2 (1e-6f * 1e-6f)

// Derived
#define HW4   ((H_ * W_) / 4)          // 4096 float4 per (b,c,t) slice
#define NCOLS (B_ * C_ * HW4)          // 262144 float4-columns
#define CPB   128                      // float4-columns per block
#define N_MAIN ((double)B_ * C_ * T_ * H_ * W_)        // 33554432
#define N_TEMP ((double)B_ * C_ * (T_ - 1) * H_ * W_)  // 32505856

struct Consts {
    float D[KF][T_];   // truncated orthonormal DCT-II rows (row 0 unused in kernel)
    float M[KF][KF];   // quadratic form for temporal-diff MSE (row/col 0 zero)
};

// Block: 256 threads = 128 columns x 2 t-halves.
// Grid: NCOLS/CPB = 2048 blocks -> 8 blocks/CU -> 32 waves/CU cap.
__global__ __launch_bounds__(256)
void loss_main_kernel(const float4* __restrict__ xs,
                      const float4* __restrict__ xt,
                      double* __restrict__ acc,
                      Consts con)
{
    const int col  = threadIdx.x & (CPB - 1);
    const int half = threadIdx.x >> 7;               // 0 or 1
    const int p    = blockIdx.x * CPB + col;         // [0, NCOLS)
    const int bc   = p >> 12;                        // p / 4096
    const int hw   = p & 4095;                       // p % 4096
    const size_t base = (size_t)bc * (T_ * HW4) + hw;
    const float4* A  = xs + base;
    const float4* Bp = xt + base;
    const int t0 = half * (T_ / 2);                  // 0 or 16

    float charb = 0.f;
    // Only AC coefficients n=1..3 matter (M row/col 0 is zero: DC is constant)
    float c[KF - 1][4];
    #pragma unroll
    for (int n = 0; n < KF - 1; ++n)
        #pragma unroll
        for (int j = 0; j < 4; ++j) c[n][j] = 0.f;

    // 16 t's per thread, in chunks of 4: 8 vector loads in flight before use
    #pragma unroll
    for (int tb = 0; tb < T_ / 2; tb += 4) {
        float4 a[4], b[4];
        #pragma unroll
        for (int u = 0; u < 4; ++u) {
            a[u] = A[(size_t)(t0 + tb + u) * HW4];
            b[u] = Bp[(size_t)(t0 + tb + u) * HW4];
        }
        #pragma unroll
        for (int u = 0; u < 4; ++u) {
            const int t = t0 + tb + u;
            float d[4];
            d[0] = a[u].x - b[u].x; d[1] = a[u].y - b[u].y;
            d[2] = a[u].z - b[u].z; d[3] = a[u].w - b[u].w;
            #pragma unroll
            for (int j = 0; j < 4; ++j)
                charb += sqrtf(fmaf(d[j], d[j], EPS2));
            #pragma unroll
            for (int n = 0; n < KF - 1; ++n) {
                const float w = con.D[n + 1][t];
                #pragma unroll
                for (int j = 0; j < 4; ++j)
                    c[n][j] = fmaf(w, d[j], c[n][j]);
            }
        }
    }

    // Exchange half-1 partial coefficients via LDS ([coef][col] layout:
    // lanes hit distinct banks -> conflict-free), combine in half-0 threads.
    __shared__ float s_c[(KF - 1) * 4][CPB];
    float quad = 0.f;
    if (half == 1) {
        #pragma unroll
        for (int n = 0; n < KF - 1; ++n)
            #pragma unroll
            for (int j = 0; j < 4; ++j)
                s_c[n * 4 + j][col] = c[n][j];
    }
    __syncthreads();
    if (half == 0) {
        #pragma unroll
        for (int n = 0; n < KF - 1; ++n)
            #pragma unroll
            for (int j = 0; j < 4; ++j)
                c[n][j] += s_c[n * 4 + j][col];
        // c^T M c over AC coefficients
        #pragma unroll
        for (int j = 0; j < 4; ++j) {
            #pragma unroll
            for (int n = 0; n < KF - 1; ++n) {
                float e = 0.f;
                #pragma unroll
                for (int m = 0; m < KF - 1; ++m)
                    e = fmaf(con.M[n + 1][m + 1], c[m][j], e);
                quad = fmaf(c[n][j], e, quad);
            }
        }
    }

    // Wave (64-lane) shuffle reduction, then cross-wave via LDS
    #pragma unroll
    for (int off = 32; off > 0; off >>= 1) {
        charb += __shfl_down(charb, off, 64);
        quad  += __shfl_down(quad,  off, 64);
    }

    __shared__ float s_ch[4], s_q[4];
    const int lane = threadIdx.x & 63;
    const int wave = threadIdx.x >> 6;
    if (lane == 0) { s_ch[wave] = charb; s_q[wave] = quad; }
    __syncthreads();

    if (threadIdx.x == 0) {
        double ch = (double)s_ch[0] + (double)s_ch[1] + (double)s_ch[2] + (double)s_ch[3];
        double q  = (double)s_q[0]  + (double)s_q[1]  + (double)s_q[2]  + (double)s_q[3];
        atomicAdd(&acc[0], ch);
        atomicAdd(&acc[1], q);
    }
}

__global__ void loss_final_kernel(const double* __restrict__ acc,
                                  float* __restrict__ out)
{
    if (threadIdx.x == 0) {
        double Lm = acc[0] / N_MAIN;
        double Lt = acc[1] / N_TEMP;
        out[0] = (float)(Lm + TAU * Lt);
        out[1] = (float)Lm;
        out[2] = (float)Lt;
    }
}

extern "C" void kernel_launch(void* const* d_in, const int* in_sizes, int n_in,
                              void* d_out, int out_size, void* d_ws, size_t ws_size,
                              hipStream_t stream)
{
    const float4* xs = (const float4*)d_in[0];
    const float4* xt = (const float4*)d_in[1];
    float* out = (float*)d_out;
    double* acc = (double*)d_ws;

    // Build DCT constants on host (cheap, deterministic, every call)
    Consts con;
    for (int n = 0; n < KF; ++n) {
        for (int t = 0; t < T_; ++t) {
            double v = sqrt(2.0 / (double)T_) *
                       cos(M_PI * (2.0 * t + 1.0) * n / (2.0 * T_));
            if (n == 0) v *= 1.0 / sqrt(2.0);
            con.D[n][t] = (float)v;
        }
    }
    for (int n = 0; n < KF; ++n) {
        for (int m = 0; m < KF; ++m) {
            double s = 0.0;
            for (int ss = 0; ss < T_ - 1; ++ss) {
                double en = (double)con.D[n][ss + 1] - (double)con.D[n][ss];
                double em = (double)con.D[m][ss + 1] - (double)con.D[m][ss];
                s += en * em;
            }
            con.M[n][m] = (float)s;
        }
    }

    hipMemsetAsync(d_ws, 0, 2 * sizeof(double), stream);

    loss_main_kernel<<<NCOLS / CPB, 256, 0, stream>>>(xs, xt, acc, con);
    loss_final_kernel<<<1, 64, 0, stream>>>(acc, out);
}

// Round 4
// 265.662 us; speedup vs baseline: 1.0669x; 1.0669x over previous
//
#include <hip/hip_runtime.h>
#include <math.h>

// Problem constants
#define B_  4
#define C_  16
#define T_  32
#define H_  128
#define W_  128
#define KF  4
#define TAU 0.1
#define EPS2 (1e-6f * 1e-6f)

// Derived
#define HW4   ((H_ * W_) / 4)          // 4096 float4 per (b,c,t) slice
#define NCOLS (B_ * C_ * HW4)          // 262144 float4-columns
#define CPB   256                      // float4-columns per block
#define N_MAIN ((double)B_ * C_ * T_ * H_ * W_)        // 33554432
#define N_TEMP ((double)B_ * C_ * (T_ - 1) * H_ * W_)  // 32505856

typedef float f4 __attribute__((ext_vector_type(4)));  // native vec: ok for nontemporal builtins

struct Consts {
    float D[KF][T_];   // truncated orthonormal DCT-II rows (row 0 unused in kernel)
    float M[KF][KF];   // quadratic form for temporal-diff MSE (row/col 0 zero)
};

__device__ inline f4 fmaf4(float w, f4 d, f4 c) {
    c.x = fmaf(w, d.x, c.x); c.y = fmaf(w, d.y, c.y);
    c.z = fmaf(w, d.z, c.z); c.w = fmaf(w, d.w, c.w);
    return c;
}

// Block: 256 threads = 4 waves. All waves cover the SAME 256 float4-columns;
// wave w handles t in [8w, 8w+8). Each thread owns 4 columns spaced 64 float4
// (1 KB) apart -> a wave's 8-load group covers two contiguous 4 KB runs
// (vs R2's eight 1 KB islands at 64 KB stride that alias to one DRAM bank).
__global__ __launch_bounds__(256)
void loss_main_kernel(const f4* __restrict__ xs,
                      const f4* __restrict__ xt,
                      double* __restrict__ acc,
                      Consts con)
{
    const int lane = threadIdx.x & 63;
    const int wave = threadIdx.x >> 6;
    const int colbase = blockIdx.x * CPB;            // aligned: no bc crossing
    const int bc = colbase >> 12;
    const int hw = (colbase & 4095) + lane;
    const f4* A  = xs + (size_t)bc * (T_ * HW4) + hw;
    const f4* Bp = xt + (size_t)bc * (T_ * HW4) + hw;
    const int t0 = wave * (T_ / 4);                  // 8 t's per wave

    float charb = 0.f;
    f4 c[3][4];                                      // AC coeffs n=1..3, 4 cols
    #pragma unroll
    for (int n = 0; n < 3; ++n)
        #pragma unroll
        for (int j = 0; j < 4; ++j) c[n][j] = (f4)(0.f);

    f4 a[4], b[4], a2[4], b2[4];
    #pragma unroll
    for (int j = 0; j < 4; ++j) {
        a[j] = __builtin_nontemporal_load(A  + (size_t)t0 * HW4 + 64 * j);
        b[j] = __builtin_nontemporal_load(Bp + (size_t)t0 * HW4 + 64 * j);
    }

    #pragma unroll
    for (int tt = 0; tt < T_ / 4; ++tt) {
        if (tt < T_ / 4 - 1) {                       // prefetch next t-plane group
            #pragma unroll
            for (int j = 0; j < 4; ++j) {
                a2[j] = __builtin_nontemporal_load(A  + (size_t)(t0 + tt + 1) * HW4 + 64 * j);
                b2[j] = __builtin_nontemporal_load(Bp + (size_t)(t0 + tt + 1) * HW4 + 64 * j);
            }
        }
        const int t = t0 + tt;
        const float w1 = con.D[1][t], w2 = con.D[2][t], w3 = con.D[3][t];
        #pragma unroll
        for (int j = 0; j < 4; ++j) {
            f4 d = a[j] - b[j];
            charb += sqrtf(fmaf(d.x, d.x, EPS2)) + sqrtf(fmaf(d.y, d.y, EPS2))
                   + sqrtf(fmaf(d.z, d.z, EPS2)) + sqrtf(fmaf(d.w, d.w, EPS2));
            c[0][j] = fmaf4(w1, d, c[0][j]);
            c[1][j] = fmaf4(w2, d, c[1][j]);
            c[2][j] = fmaf4(w3, d, c[2][j]);
        }
        if (tt < T_ / 4 - 1) {
            #pragma unroll
            for (int j = 0; j < 4; ++j) { a[j] = a2[j]; b[j] = b2[j]; }
        }
    }

    // Combine per-wave partial coefficients (linear in t) via LDS.
    // Layout [src_wave][coef][lane]: consecutive lanes -> consecutive float4,
    // the optimal pattern for b128 LDS access.
    __shared__ f4 s_c[3][12][64];
    if (wave != 0) {
        #pragma unroll
        for (int n = 0; n < 3; ++n)
            #pragma unroll
            for (int j = 0; j < 4; ++j)
                s_c[wave - 1][n * 4 + j][lane] = c[n][j];
    }
    __syncthreads();

    float quad = 0.f;
    if (wave == 0) {
        #pragma unroll
        for (int n = 0; n < 3; ++n)
            #pragma unroll
            for (int j = 0; j < 4; ++j) {
                f4 v = c[n][j];
                #pragma unroll
                for (int s = 0; s < 3; ++s)
                    v += s_c[s][n * 4 + j][lane];
                c[n][j] = v;
            }
        // quad = c^T M c over AC coefficients, per scalar column
        #pragma unroll
        for (int j = 0; j < 4; ++j) {
            #pragma unroll
            for (int n = 0; n < 3; ++n) {
                f4 e = (f4)(0.f);
                #pragma unroll
                for (int m = 0; m < 3; ++m)
                    e = fmaf4(con.M[n + 1][m + 1], c[m][j], e);
                quad = fmaf(c[n][j].x, e.x, quad);
                quad = fmaf(c[n][j].y, e.y, quad);
                quad = fmaf(c[n][j].z, e.z, quad);
                quad = fmaf(c[n][j].w, e.w, quad);
            }
        }
    }

    // Wave shuffle reduction, then cross-wave via LDS
    #pragma unroll
    for (int off = 32; off > 0; off >>= 1) {
        charb += __shfl_down(charb, off, 64);
        quad  += __shfl_down(quad,  off, 64);
    }

    __shared__ float s_ch[4], s_q[4];
    if (lane == 0) { s_ch[wave] = charb; s_q[wave] = quad; }
    __syncthreads();

    if (threadIdx.x == 0) {
        double ch = (double)s_ch[0] + (double)s_ch[1] + (double)s_ch[2] + (double)s_ch[3];
        double q  = (double)s_q[0]  + (double)s_q[1]  + (double)s_q[2]  + (double)s_q[3];
        atomicAdd(&acc[0], ch);
        atomicAdd(&acc[1], q);
    }
}

__global__ void loss_final_kernel(const double* __restrict__ acc,
                                  float* __restrict__ out)
{
    if (threadIdx.x == 0) {
        double Lm = acc[0] / N_MAIN;
        double Lt = acc[1] / N_TEMP;
        out[0] = (float)(Lm + TAU * Lt);
        out[1] = (float)Lm;
        out[2] = (float)Lt;
    }
}

extern "C" void kernel_launch(void* const* d_in, const int* in_sizes, int n_in,
                              void* d_out, int out_size, void* d_ws, size_t ws_size,
                              hipStream_t stream)
{
    const f4* xs = (const f4*)d_in[0];
    const f4* xt = (const f4*)d_in[1];
    float* out = (float*)d_out;
    double* acc = (double*)d_ws;

    // Build DCT constants on host (cheap, deterministic, every call)
    Consts con;
    for (int n = 0; n < KF; ++n) {
        for (int t = 0; t < T_; ++t) {
            double v = sqrt(2.0 / (double)T_) *
                       cos(M_PI * (2.0 * t + 1.0) * n / (2.0 * T_));
            if (n == 0) v *= 1.0 / sqrt(2.0);
            con.D[n][t] = (float)v;
        }
    }
    for (int n = 0; n < KF; ++n) {
        for (int m = 0; m < KF; ++m) {
            double s = 0.0;
            for (int ss = 0; ss < T_ - 1; ++ss) {
                double en = (double)con.D[n][ss + 1] - (double)con.D[n][ss];
                double em = (double)con.D[m][ss + 1] - (double)con.D[m][ss];
                s += en * em;
            }
            con.M[n][m] = (float)s;
        }
    }

    (void)hipMemsetAsync(d_ws, 0, 2 * sizeof(double), stream);

    loss_main_kernel<<<NCOLS / CPB, 256, 0, stream>>>(xs, xt, acc, con);
    loss_final_kernel<<<1, 64, 0, stream>>>(acc, out);
}

// Round 5
// 257.977 us; speedup vs baseline: 1.0987x; 1.0298x over previous
//
#include <hip/hip_runtime.h>
#include <math.h>

// Problem constants
#define B_  4
#define C_  16
#define T_  32
#define H_  128
#define W_  128
#define KF  4
#define TAU 0.1
#define EPS2 (1e-6f * 1e-6f)

// Derived
#define HW4   ((H_ * W_) / 4)          // 4096 float4 per (b,c,t) slice
#define NCOLS (B_ * C_ * HW4)          // 262144 float4-columns
#define CPB   256                      // float4-columns per block
#define NBLK  (NCOLS / CPB)            // 1024 blocks
#define N_MAIN ((double)B_ * C_ * T_ * H_ * W_)        // 33554432
#define N_TEMP ((double)B_ * C_ * (T_ - 1) * H_ * W_)  // 32505856

typedef float f4 __attribute__((ext_vector_type(4)));  // native vec: ok for nontemporal builtins

struct Consts {
    float D[KF][T_];   // truncated orthonormal DCT-II rows (row 0 unused in kernel)
    float M[KF][KF];   // quadratic form for temporal-diff MSE (row/col 0 zero)
};

__device__ inline f4 fmaf4(float w, f4 d, f4 c) {
    c.x = fmaf(w, d.x, c.x); c.y = fmaf(w, d.y, c.y);
    c.z = fmaf(w, d.z, c.z); c.w = fmaf(w, d.w, c.w);
    return c;
}

// Block: 256 threads = 4 waves. All waves cover the SAME 256 float4-columns;
// wave w handles t in [8w, 8w+8). Each thread owns 4 columns spaced 64 float4
// (1 KB) apart -> a wave's 8-load group covers two contiguous 4 KB runs
// (vs eight 1 KB islands at 64 KB stride that alias to one DRAM bank).
// Partials go to d_ws[2*blockIdx] (no atomics -> no tail serialization,
// no memset needed since every slot is overwritten).
__global__ __launch_bounds__(256)
void loss_main_kernel(const f4* __restrict__ xs,
                      const f4* __restrict__ xt,
                      double* __restrict__ part,
                      Consts con)
{
    const int lane = threadIdx.x & 63;
    const int wave = threadIdx.x >> 6;
    const int colbase = blockIdx.x * CPB;            // aligned: no bc crossing
    const int bc = colbase >> 12;
    const int hw = (colbase & 4095) + lane;
    const f4* A  = xs + (size_t)bc * (T_ * HW4) + hw;
    const f4* Bp = xt + (size_t)bc * (T_ * HW4) + hw;
    const int t0 = wave * (T_ / 4);                  // 8 t's per wave

    float charb = 0.f;
    f4 c[3][4];                                      // AC coeffs n=1..3, 4 cols
    #pragma unroll
    for (int n = 0; n < 3; ++n)
        #pragma unroll
        for (int j = 0; j < 4; ++j) c[n][j] = (f4)(0.f);

    f4 a[4], b[4], a2[4], b2[4];
    #pragma unroll
    for (int j = 0; j < 4; ++j) {
        a[j] = __builtin_nontemporal_load(A  + (size_t)t0 * HW4 + 64 * j);
        b[j] = __builtin_nontemporal_load(Bp + (size_t)t0 * HW4 + 64 * j);
    }

    #pragma unroll
    for (int tt = 0; tt < T_ / 4; ++tt) {
        if (tt < T_ / 4 - 1) {                       // prefetch next t-plane group
            #pragma unroll
            for (int j = 0; j < 4; ++j) {
                a2[j] = __builtin_nontemporal_load(A  + (size_t)(t0 + tt + 1) * HW4 + 64 * j);
                b2[j] = __builtin_nontemporal_load(Bp + (size_t)(t0 + tt + 1) * HW4 + 64 * j);
            }
        }
        const int t = t0 + tt;
        const float w1 = con.D[1][t], w2 = con.D[2][t], w3 = con.D[3][t];
        #pragma unroll
        for (int j = 0; j < 4; ++j) {
            f4 d = a[j] - b[j];
            charb += sqrtf(fmaf(d.x, d.x, EPS2)) + sqrtf(fmaf(d.y, d.y, EPS2))
                   + sqrtf(fmaf(d.z, d.z, EPS2)) + sqrtf(fmaf(d.w, d.w, EPS2));
            c[0][j] = fmaf4(w1, d, c[0][j]);
            c[1][j] = fmaf4(w2, d, c[1][j]);
            c[2][j] = fmaf4(w3, d, c[2][j]);
        }
        if (tt < T_ / 4 - 1) {
            #pragma unroll
            for (int j = 0; j < 4; ++j) { a[j] = a2[j]; b[j] = b2[j]; }
        }
    }

    // Combine per-wave partial coefficients (linear in t) via LDS.
    __shared__ f4 s_c[3][12][64];
    if (wave != 0) {
        #pragma unroll
        for (int n = 0; n < 3; ++n)
            #pragma unroll
            for (int j = 0; j < 4; ++j)
                s_c[wave - 1][n * 4 + j][lane] = c[n][j];
    }
    __syncthreads();

    float quad = 0.f;
    if (wave == 0) {
        #pragma unroll
        for (int n = 0; n < 3; ++n)
            #pragma unroll
            for (int j = 0; j < 4; ++j) {
                f4 v = c[n][j];
                #pragma unroll
                for (int s = 0; s < 3; ++s)
                    v += s_c[s][n * 4 + j][lane];
                c[n][j] = v;
            }
        // quad = c^T M c over AC coefficients, per scalar column
        #pragma unroll
        for (int j = 0; j < 4; ++j) {
            #pragma unroll
            for (int n = 0; n < 3; ++n) {
                f4 e = (f4)(0.f);
                #pragma unroll
                for (int m = 0; m < 3; ++m)
                    e = fmaf4(con.M[n + 1][m + 1], c[m][j], e);
                quad = fmaf(c[n][j].x, e.x, quad);
                quad = fmaf(c[n][j].y, e.y, quad);
                quad = fmaf(c[n][j].z, e.z, quad);
                quad = fmaf(c[n][j].w, e.w, quad);
            }
        }
    }

    // Wave shuffle reduction, then cross-wave via LDS
    #pragma unroll
    for (int off = 32; off > 0; off >>= 1) {
        charb += __shfl_down(charb, off, 64);
        quad  += __shfl_down(quad,  off, 64);
    }

    __shared__ float s_ch[4], s_q[4];
    if (lane == 0) { s_ch[wave] = charb; s_q[wave] = quad; }
    __syncthreads();

    if (threadIdx.x == 0) {
        double ch = (double)s_ch[0] + (double)s_ch[1] + (double)s_ch[2] + (double)s_ch[3];
        double q  = (double)s_q[0]  + (double)s_q[1]  + (double)s_q[2]  + (double)s_q[3];
        part[2 * blockIdx.x]     = ch;   // contention-free partial write
        part[2 * blockIdx.x + 1] = q;
    }
}

__global__ __launch_bounds__(256)
void loss_final_kernel(const double* __restrict__ part,
                       float* __restrict__ out)
{
    const int tid = threadIdx.x;
    double ch = 0.0, q = 0.0;
    for (int i = tid; i < NBLK; i += 256) {
        ch += part[2 * i];
        q  += part[2 * i + 1];
    }
    #pragma unroll
    for (int off = 32; off > 0; off >>= 1) {
        ch += __shfl_down(ch, off, 64);
        q  += __shfl_down(q,  off, 64);
    }
    __shared__ double s_ch[4], s_q[4];
    const int lane = tid & 63, wave = tid >> 6;
    if (lane == 0) { s_ch[wave] = ch; s_q[wave] = q; }
    __syncthreads();
    if (tid == 0) {
        double Lm = (s_ch[0] + s_ch[1] + s_ch[2] + s_ch[3]) / N_MAIN;
        double Lt = (s_q[0] + s_q[1] + s_q[2] + s_q[3]) / N_TEMP;
        out[0] = (float)(Lm + TAU * Lt);
        out[1] = (float)Lm;
        out[2] = (float)Lt;
    }
}

extern "C" void kernel_launch(void* const* d_in, const int* in_sizes, int n_in,
                              void* d_out, int out_size, void* d_ws, size_t ws_size,
                              hipStream_t stream)
{
    const f4* xs = (const f4*)d_in[0];
    const f4* xt = (const f4*)d_in[1];
    float* out = (float*)d_out;
    double* part = (double*)d_ws;      // 2*NBLK doubles = 16 KB, fully overwritten

    // Build DCT constants on host (cheap, deterministic, every call)
    Consts con;
    for (int n = 0; n < KF; ++n) {
        for (int t = 0; t < T_; ++t) {
            double v = sqrt(2.0 / (double)T_) *
                       cos(M_PI * (2.0 * t + 1.0) * n / (2.0 * T_));
            if (n == 0) v *= 1.0 / sqrt(2.0);
            con.D[n][t] = (float)v;
        }
    }
    for (int n = 0; n < KF; ++n) {
        for (int m = 0; m < KF; ++m) {
            double s = 0.0;
            for (int ss = 0; ss < T_ - 1; ++ss) {
                double en = (double)con.D[n][ss + 1] - (double)con.D[n][ss];
                double em = (double)con.D[m][ss + 1] - (double)con.D[m][ss];
                s += en * em;
            }
            con.M[n][m] = (float)s;
        }
    }

    loss_main_kernel<<<NBLK, 256, 0, stream>>>(xs, xt, part, con);
    loss_final_kernel<<<1, 256, 0, stream>>>(part, out);
}